// Round 2
// baseline (776.203 us; speedup 1.0000x reference)
//
#include <hip/hip_runtime.h>
#include <hip/hip_bf16.h>
#include <stdint.h>

// ---------------------------------------------------------------------------
// LSTMAggregator: out = relu(self@W_self + h[len-1]@W_neigh), h from LSTM over
// neig_vecs. Fused persistent-block design:
//   k_pack : weights -> bf16 MFMA-fragment order in ws (Wc=[kernel;rec], Wout)
//   k_len  : length[b] = max(#nonzero rows, 1)
//   k_main : 256 blocks x 512 thr (8 waves) x 64 batch rows; per step t:
//            z = [x_t|h] @ Wc (K=256, MFMA 16x16x32 bf16, weights in VGPRs),
//            gates lane-local (wave w owns N-tiles {w,w+8,w+16,w+24} = i,f,g,o
//            for hcols [16w,16w+16)), h -> swizzled LDS for next step's A-frags.
//            x double-buffered in LDS via global_load_lds (pre-swizzled source).
// ---------------------------------------------------------------------------

typedef __attribute__((ext_vector_type(8))) short bf16x8;
typedef __attribute__((ext_vector_type(4))) float f32x4;

#define MFMA16(a, b, c) __builtin_amdgcn_mfma_f32_16x16x32_bf16(a, b, c, 0, 0, 0)

#define NB      16384
#define TSEQ    25
#define DIM     128     // D = H = OUT = 128
#define G4      512     // 4H
#define ROWSTRB (TSEQ * DIM * 4)   // bytes per batch row of neig_vecs = 12800

// ws layout (bytes)
#define WC_OFF    0                       // 256 frags * 1024 B
#define WOUT_OFF  (256 * 1024)            // 64 frags * 1024 B
#define LEN_OFF   (256 * 1024 + 64 * 1024) // 16384 * 4 B

__device__ __forceinline__ unsigned short bf16_bits(float f) {
  unsigned u = __builtin_bit_cast(unsigned, f);
  u += 0x7FFFu + ((u >> 16) & 1u);
  return (unsigned short)(u >> 16);
}

__device__ __forceinline__ unsigned pk2(float lo, float hi) {
  return (unsigned)bf16_bits(lo) | ((unsigned)bf16_bits(hi) << 16);
}

__device__ __forceinline__ bf16x8 cvt8(f32x4 a, f32x4 b) {
  union { bf16x8 v; unsigned u[4]; } r;
  r.u[0] = pk2(a[0], a[1]);
  r.u[1] = pk2(a[2], a[3]);
  r.u[2] = pk2(b[0], b[1]);
  r.u[3] = pk2(b[2], b[3]);
  return r.v;
}

__device__ __forceinline__ void gload_lds16(const void* g, void* l) {
  __builtin_amdgcn_global_load_lds(
      (const __attribute__((address_space(1))) unsigned int*)g,
      (__attribute__((address_space(3))) unsigned int*)l, 16, 0, 0);
}

#define L2E 1.4426950408889634f
__device__ __forceinline__ float sigm(float x) {
  return __builtin_amdgcn_rcpf(1.0f + __builtin_amdgcn_exp2f(-L2E * x));
}
__device__ __forceinline__ float tanh_(float x) {
  return 2.0f * __builtin_amdgcn_rcpf(1.0f + __builtin_amdgcn_exp2f(-2.0f * L2E * x)) - 1.0f;
}

// ---------------------------------------------------------------------------
// k_pack: Wc frag f = w*32 + j*8 + kk (w:wave 0..7, j:gate 0..3, kk:K-tile 0..7)
//   B[k][col], col = (w+8j)*16 + (lane&15), k = kk*32 + (lane>>4)*8 + i
//   k<128 -> kernel, else rec_kernel. Wout frag f = w*8 + kk similarly
//   (k<128 -> W_self, else W_neigh), col = w*16 + (lane&15).
// ---------------------------------------------------------------------------
__global__ void k_pack(const float* __restrict__ kern, const float* __restrict__ rec,
                       const float* __restrict__ wself, const float* __restrict__ wneigh,
                       unsigned char* __restrict__ ws) {
  int tid = blockIdx.x * 256 + threadIdx.x;
  if (tid < 16384) {
    int frag = tid >> 6, lane = tid & 63;
    int w = frag >> 5, j = (frag >> 3) & 3, kk = frag & 7;
    int col = (w + 8 * j) * 16 + (lane & 15);
    int k0 = kk * 32 + (lane >> 4) * 8;
    unsigned u[4];
    #pragma unroll
    for (int p = 0; p < 4; ++p) {
      int ka = k0 + 2 * p, kb = ka + 1;
      float va = (ka < 128) ? kern[ka * G4 + col] : rec[(ka - 128) * G4 + col];
      float vb = (kb < 128) ? kern[kb * G4 + col] : rec[(kb - 128) * G4 + col];
      u[p] = (unsigned)bf16_bits(va) | ((unsigned)bf16_bits(vb) << 16);
    }
    uint4 o = make_uint4(u[0], u[1], u[2], u[3]);
    *(uint4*)(ws + WC_OFF + (size_t)frag * 1024 + lane * 16) = o;
  } else if (tid < 16384 + 4096) {
    int t2 = tid - 16384;
    int frag = t2 >> 6, lane = t2 & 63;
    int w = frag >> 3, kk = frag & 7;
    int col = w * 16 + (lane & 15);
    int k0 = kk * 32 + (lane >> 4) * 8;
    unsigned u[4];
    #pragma unroll
    for (int p = 0; p < 4; ++p) {
      int ka = k0 + 2 * p, kb = ka + 1;
      float va = (ka < 128) ? wself[ka * DIM + col] : wneigh[(ka - 128) * DIM + col];
      float vb = (kb < 128) ? wself[kb * DIM + col] : wneigh[(kb - 128) * DIM + col];
      u[p] = (unsigned)bf16_bits(va) | ((unsigned)bf16_bits(vb) << 16);
    }
    uint4 o = make_uint4(u[0], u[1], u[2], u[3]);
    *(uint4*)(ws + WOUT_OFF + (size_t)frag * 1024 + lane * 16) = o;
  }
}

// ---------------------------------------------------------------------------
// k_len: one wave per batch row; length = max(#t with any nonzero, 1)
// ---------------------------------------------------------------------------
__global__ void k_len(const float* __restrict__ neig, int* __restrict__ len) {
  int wid = (blockIdx.x * 256 + threadIdx.x) >> 6;
  int lane = threadIdx.x & 63;
  if (wid >= NB) return;
  const float* base = neig + (size_t)wid * TSEQ * DIM;
  int cnt = 0;
  for (int t = 0; t < TSEQ; ++t) {
    float2 v = *(const float2*)(base + t * DIM + lane * 2);
    cnt += (__any(v.x != 0.0f || v.y != 0.0f) ? 1 : 0);
  }
  if (lane == 0) len[wid] = cnt > 0 ? cnt : 1;
}

// ---------------------------------------------------------------------------
// k_main
// LDS: [0,65536)   x double buffer, f32, [2][64 rows][512 B], 16B-chunk index
//                  physically stored at (chunk ^ (row&7))  (via source swizzle)
//      [65536,81920) h bf16 [64][256 B], chunk16 stored at (chunk ^ (row&7))
// ---------------------------------------------------------------------------
__launch_bounds__(512, 2)
__global__ void k_main(const float* __restrict__ self, const float* __restrict__ neig,
                       const float* __restrict__ bias, const unsigned char* __restrict__ ws,
                       float* __restrict__ out) {
  __shared__ alignas(16) unsigned char smem[81920];
  const int tid  = threadIdx.x;
  const int lane = tid & 63;
  const int w    = tid >> 6;        // wave 0..7
  const int qh   = lane >> 4;       // 0..3
  const int ql   = lane & 15;
  const int b0   = blockIdx.x * 64;

  // --- persistent B fragments: bw[gate j][kk]
  bf16x8 bw[4][8];
  {
    const unsigned char* base = ws + WC_OFF + (size_t)(w * 32) * 1024 + lane * 16;
    #pragma unroll
    for (int j = 0; j < 4; ++j)
      #pragma unroll
      for (int kk = 0; kk < 8; ++kk)
        bw[j][kk] = *(const bf16x8*)(base + (j * 8 + kk) * 1024);
  }
  // --- per-gate bias at this lane's hcol
  float bgate[4];
  #pragma unroll
  for (int j = 0; j < 4; ++j) bgate[j] = bias[j * 128 + w * 16 + ql];
  // --- lengths for the 16 rows this lane's C-fragments touch, packed u8x4
  const int* lenp = (const int*)(ws + LEN_OFF);
  unsigned lp[4];
  #pragma unroll
  for (int m = 0; m < 4; ++m) {
    unsigned v = 0;
    #pragma unroll
    for (int r = 0; r < 4; ++r)
      v |= ((unsigned)lenp[b0 + 16 * m + qh * 4 + r]) << (8 * r);
    lp[m] = v;
  }
  // --- state
  f32x4 c[4];
  #pragma unroll
  for (int m = 0; m < 4; ++m) c[m] = (f32x4){0.f, 0.f, 0.f, 0.f};
  unsigned hcap[4][2] = {{0u,0u},{0u,0u},{0u,0u},{0u,0u}};  // packed bf16 pairs

  // --- zero lds_h
  *(uint4*)(smem + 65536 + tid * 32)      = make_uint4(0, 0, 0, 0);
  *(uint4*)(smem + 65536 + tid * 32 + 16) = make_uint4(0, 0, 0, 0);

  // --- staging lane offsets (wave w stages rows [8w, 8w+8), 2 rows/issue)
  unsigned voff[4];
  #pragma unroll
  for (int i = 0; i < 4; ++i) {
    int row = 8 * w + 2 * i + (lane >> 5);
    int ch  = (lane & 31) ^ (row & 7);          // logical chunk fetched
    voff[i] = (unsigned)(row * ROWSTRB + ch * 16);
  }
  const unsigned char* gneig = (const unsigned char*)neig + (size_t)b0 * ROWSTRB;

  // --- prologue: stage t=0 into buf0
  #pragma unroll
  for (int i = 0; i < 4; ++i)
    gload_lds16(gneig + voff[i], smem + (8 * w + 2 * i) * 512);
  asm volatile("s_waitcnt vmcnt(0)" ::: "memory");
  __syncthreads();

  int cur = 0;
  for (int t = 0; t < TSEQ; ++t) {
    // (0) stage t+1 (clamped; t=24 restages harmlessly) into buf cur^1
    {
      int tn = (t < TSEQ - 1) ? t + 1 : TSEQ - 1;
      const unsigned char* g = gneig + tn * 512;
      unsigned lb = (unsigned)((cur ^ 1) * 32768);
      #pragma unroll
      for (int i = 0; i < 4; ++i)
        gload_lds16(g + voff[i], smem + lb + (8 * w + 2 * i) * 512);
    }
    // (1) GEMM: z = [x_t | h] @ Wc
    f32x4 acc[4][4];
    #pragma unroll
    for (int m = 0; m < 4; ++m)
      #pragma unroll
      for (int j = 0; j < 4; ++j) acc[m][j] = (f32x4){0.f, 0.f, 0.f, 0.f};
    {
      const unsigned xb = (unsigned)(cur * 32768);
      #pragma unroll
      for (int m = 0; m < 4; ++m) {
        const int row = 16 * m + ql;
        const int rs  = row & 7;
        // x-part (kk 0..3), f32 in LDS -> bf16 frags
        #pragma unroll
        for (int kk = 0; kk < 4; ++kk) {
          int c0 = kk * 8 + qh * 2;
          f32x4 v0 = *(const f32x4*)(smem + xb + row * 512 + ((c0)     ^ rs) * 16);
          f32x4 v1 = *(const f32x4*)(smem + xb + row * 512 + ((c0 + 1) ^ rs) * 16);
          bf16x8 a = cvt8(v0, v1);
          #pragma unroll
          for (int j = 0; j < 4; ++j)
            acc[m][j] = MFMA16(a, bw[j][kk], acc[m][j]);
        }
        // h-part (kk 4..7), bf16 in LDS
        #pragma unroll
        for (int kk = 0; kk < 4; ++kk) {
          bf16x8 a = *(const bf16x8*)(smem + 65536 + row * 256 + ((kk * 4 + qh) ^ rs) * 16);
          #pragma unroll
          for (int j = 0; j < 4; ++j)
            acc[m][j] = MFMA16(a, bw[j][kk + 4], acc[m][j]);
        }
      }
    }
    __syncthreads();   // (2) all lds_h reads done before overwrite
    // (3) gates + h write + capture
    const unsigned tp1 = (unsigned)(t + 1);
    #pragma unroll
    for (int m = 0; m < 4; ++m) {
      float hh[4];
      #pragma unroll
      for (int r = 0; r < 4; ++r) {
        float ii = sigm(acc[m][0][r] + bgate[0]);
        float ff = sigm(acc[m][1][r] + bgate[1]);
        float gg = tanh_(acc[m][2][r] + bgate[2]);
        float oo = sigm(acc[m][3][r] + bgate[3]);
        float cc = ff * c[m][r] + ii * gg;
        c[m][r] = cc;
        hh[r] = oo * tanh_(cc);
      }
      // write h (bf16) to lds_h: row = 16m + qh*4 + r, hcol = 16w + ql
      #pragma unroll
      for (int r = 0; r < 4; ++r) {
        int row = 16 * m + qh * 4 + r;
        unsigned addr = 65536u + row * 256 + (((2 * w + (ql >> 3)) ^ (row & 7)) * 16) + (ql & 7) * 2;
        *(unsigned short*)(smem + addr) = bf16_bits(hh[r]);
      }
      // capture h at t == len-1 (packed bf16 pairs, byte-masked merge)
      #pragma unroll
      for (int p = 0; p < 2; ++p) {
        unsigned pk = pk2(hh[2 * p], hh[2 * p + 1]);
        unsigned m0 = (((lp[m] >> (16 * p))     & 255u) == tp1) ? 0x0000FFFFu : 0u;
        unsigned m1 = (((lp[m] >> (16 * p + 8)) & 255u) == tp1) ? 0xFFFF0000u : 0u;
        unsigned msk = m0 | m1;
        hcap[m][p] = (msk & pk) | (~msk & hcap[m][p]);
      }
    }
    asm volatile("s_waitcnt vmcnt(0)" ::: "memory");  // (4) next-x DMA done
    __syncthreads();                                  // (5)
    cur ^= 1;
  }

  // ----- epilogue: out = relu(self@W_self + hcap@W_neigh)
  // stage self (bf16) into smem[0..16384) as [64][256 B], swizzled like lds_h
  {
    int row = tid >> 3, seg = tid & 7;
    const float* src = self + (size_t)(b0 + row) * DIM + seg * 16;
    float4 f0 = *(const float4*)(src);
    float4 f1 = *(const float4*)(src + 4);
    float4 f2 = *(const float4*)(src + 8);
    float4 f3 = *(const float4*)(src + 12);
    uint4 o0 = make_uint4(pk2(f0.x, f0.y), pk2(f0.z, f0.w), pk2(f1.x, f1.y), pk2(f1.z, f1.w));
    uint4 o1 = make_uint4(pk2(f2.x, f2.y), pk2(f2.z, f2.w), pk2(f3.x, f3.y), pk2(f3.z, f3.w));
    int rs = row & 7;
    *(uint4*)(smem + row * 256 + ((seg * 2)     ^ rs) * 16) = o0;
    *(uint4*)(smem + row * 256 + ((seg * 2 + 1) ^ rs) * 16) = o1;
  }
  // write hcap into lds_h (overwrites wave-local cells only)
  #pragma unroll
  for (int m = 0; m < 4; ++m)
    #pragma unroll
    for (int p = 0; p < 2; ++p)
      #pragma unroll
      for (int hi2 = 0; hi2 < 2; ++hi2) {
        int r = 2 * p + hi2;
        int row = 16 * m + qh * 4 + r;
        unsigned addr = 65536u + row * 256 + (((2 * w + (ql >> 3)) ^ (row & 7)) * 16) + (ql & 7) * 2;
        *(unsigned short*)(smem + addr) = (unsigned short)((hcap[m][p] >> (16 * hi2)) & 0xFFFFu);
      }
  __syncthreads();
  // Wout fragments for this wave's 16 out-cols
  bf16x8 bo[8];
  #pragma unroll
  for (int kk = 0; kk < 8; ++kk)
    bo[kk] = *(const bf16x8*)(ws + WOUT_OFF + (size_t)(w * 8 + kk) * 1024 + lane * 16);
  #pragma unroll
  for (int m = 0; m < 4; ++m) {
    const int row = 16 * m + ql;
    const int rs  = row & 7;
    f32x4 a2 = (f32x4){0.f, 0.f, 0.f, 0.f};
    #pragma unroll
    for (int kk = 0; kk < 4; ++kk) {
      bf16x8 a = *(const bf16x8*)(smem + row * 256 + ((kk * 4 + qh) ^ rs) * 16);
      a2 = MFMA16(a, bo[kk], a2);
    }
    #pragma unroll
    for (int kk = 0; kk < 4; ++kk) {
      bf16x8 a = *(const bf16x8*)(smem + 65536 + row * 256 + ((kk * 4 + qh) ^ rs) * 16);
      a2 = MFMA16(a, bo[kk + 4], a2);
    }
    #pragma unroll
    for (int r = 0; r < 4; ++r) {
      float v = a2[r] > 0.0f ? a2[r] : 0.0f;
      out[(size_t)(b0 + 16 * m + qh * 4 + r) * DIM + w * 16 + ql] = v;
    }
  }
}

extern "C" void kernel_launch(void* const* d_in, const int* in_sizes, int n_in,
                              void* d_out, int out_size, void* d_ws, size_t ws_size,
                              hipStream_t stream) {
  const float* self   = (const float*)d_in[0];
  const float* neig   = (const float*)d_in[1];
  const float* kern   = (const float*)d_in[2];
  const float* rec    = (const float*)d_in[3];
  const float* lbias  = (const float*)d_in[4];
  const float* wself  = (const float*)d_in[5];
  const float* wneigh = (const float*)d_in[6];
  float* out = (float*)d_out;
  unsigned char* ws = (unsigned char*)d_ws;

  k_pack<<<80, 256, 0, stream>>>(kern, rec, wself, wneigh, ws);
  k_len<<<4096, 256, 0, stream>>>(neig, (int*)(ws + LEN_OFF));
  k_main<<<256, 512, 0, stream>>>(self, neig, lbias, ws, out);
}